// Round 7
// baseline (294.527 us; speedup 1.0000x reference)
//
#include <hip/hip_runtime.h>

#define LOG2E 1.44269504088896340736f

typedef short v8s __attribute__((ext_vector_type(8)));
typedef float v4f __attribute__((ext_vector_type(4)));
typedef unsigned int v2u __attribute__((ext_vector_type(2)));

__device__ __forceinline__ unsigned short f2bf(float f) {
  unsigned int u = __float_as_uint(f);
  u += 0x7fffu + ((u >> 16) & 1u);   // RNE
  return (unsigned short)(u >> 16);
}

__device__ __forceinline__ unsigned int cvtpk(float lo, float hi) {
  unsigned int r;
  asm("v_cvt_pk_bf16_f32 %0, %1, %2" : "=v"(r) : "v"(lo), "v"(hi));
  return r;
}

__device__ __forceinline__ void gld16(const void* g, void* l) {
  __builtin_amdgcn_global_load_lds(
      (const __attribute__((address_space(1))) unsigned int*)g,
      (__attribute__((address_space(3))) unsigned int*)l, 16, 0, 0);
}

#define MFMA16(a, b, c) __builtin_amdgcn_mfma_f32_16x16x32_bf16((a), (b), (c), 0, 0, 0)

static const int CCH = 256, NPIX = 4096;

// ---------------- prep1: x transpose + weight conversion (fused) ----------------
__global__ void prep1_kernel(const float* __restrict__ x, const float* __restrict__ Wq,
                             const float* __restrict__ Wk, const float* __restrict__ Wv,
                             unsigned short* __restrict__ xT, unsigned short* __restrict__ wqk,
                             unsigned short* __restrict__ wvb) {
  __shared__ float tile[64][65];
  if (blockIdx.x >= 2048) {
    // weight conversion: 64 blocks grid-stride
    int idx = (blockIdx.x - 2048) * 256 + threadIdx.x;
    int tot = 64 * 256 + 256 * 256;
    for (int i = idx; i < tot; i += 64 * 256) {
      if (i < 64 * 256) {
        float v = (i < 32 * 256) ? Wq[i] : Wk[i - 32 * 256];
        wqk[i] = f2bf(v);
      } else {
        wvb[i - 64 * 256] = f2bf(Wv[i - 64 * 256]);
      }
    }
    return;
  }
  int bid = blockIdx.x;                 // 8 * 4 * 64
  int b = bid >> 8;
  int c0 = ((bid >> 6) & 3) * 64;
  int n0 = (bid & 63) * 64;
  int t = threadIdx.x;
  const float* xp = x + ((size_t)b * CCH + c0) * NPIX + n0;
#pragma unroll
  for (int p = 0; p < 16; ++p) {
    int cc = p * 4 + (t >> 6);
    int nn = t & 63;
    tile[cc][nn] = xp[(size_t)cc * NPIX + nn];
  }
  __syncthreads();
  unsigned short* xo = xT + ((size_t)b * NPIX + n0) * CCH + c0;
#pragma unroll
  for (int p = 0; p < 8; ++p) {
    int nn = p * 8 + (t >> 5);
    int cc = (t & 31) * 2;
    unsigned int pk = (unsigned int)f2bf(tile[cc][nn]) |
                      ((unsigned int)f2bf(tile[cc + 1][nn]) << 16);
    *(unsigned int*)(xo + (size_t)nn * CCH + cc) = pk;
  }
}

// ---------------- prep2: q/k projection + v projection (fused) ----------------
__global__ __launch_bounds__(256, 2) void prep2_kernel(
    const unsigned short* __restrict__ xT, const unsigned short* __restrict__ wqk,
    const unsigned short* __restrict__ wvb, const float* __restrict__ bq,
    const float* __restrict__ bk, const float* __restrict__ bv,
    unsigned short* __restrict__ qb, unsigned short* __restrict__ kb,
    unsigned short* __restrict__ vb) {
  int w = threadIdx.x >> 6, lane = threadIdx.x & 63, g = lane >> 4, li = lane & 15;
  if (blockIdx.x < 512) {
    // ---- q/k projection: q,k [B,N,32] bf16 ----
    int bid = blockIdx.x;
    int b = bid >> 6;
    int n0 = (bid & 63) * 64;
    int nrow = n0 + 16 * w;
    v4f acc[4];
#pragma unroll
    for (int dt = 0; dt < 4; ++dt) acc[dt] = (v4f){0.f, 0.f, 0.f, 0.f};
#pragma unroll
    for (int ks = 0; ks < 8; ++ks) {
      v8s a = *(const v8s*)(xT + ((size_t)(b * NPIX + nrow + li)) * CCH + ks * 32 + g * 8);
#pragma unroll
      for (int dt = 0; dt < 4; ++dt) {
        v8s bf = *(const v8s*)(wqk + (dt * 16 + li) * 256 + ks * 32 + g * 8);
        acc[dt] = MFMA16(a, bf, acc[dt]);
      }
    }
#pragma unroll
    for (int dt = 0; dt < 4; ++dt) {
      int d = (dt & 1) * 16 + li;
      float bias = (dt < 2) ? bq[d] : bk[d];
      unsigned short* op = (dt < 2) ? qb : kb;
#pragma unroll
      for (int r = 0; r < 4; ++r) {
        int n = nrow + 4 * g + r;
        op[((size_t)(b * NPIX + n)) * 32 + d] = f2bf(acc[dt][r] + bias);
      }
    }
  } else {
    // ---- v projection: V [B,C,N] bf16 ----
    int bid = blockIdx.x - 512;
    int b = bid >> 6;
    int n0 = (bid & 63) * 64;
    v4f acc[4][4];
#pragma unroll
    for (int ct = 0; ct < 4; ++ct)
#pragma unroll
      for (int nt = 0; nt < 4; ++nt) acc[ct][nt] = (v4f){0.f, 0.f, 0.f, 0.f};
#pragma unroll
    for (int ks = 0; ks < 8; ++ks) {
      v8s xf[4];
#pragma unroll
      for (int nt = 0; nt < 4; ++nt)
        xf[nt] = *(const v8s*)(xT + ((size_t)(b * NPIX + n0 + nt * 16 + li)) * CCH + ks * 32 + g * 8);
#pragma unroll
      for (int ct = 0; ct < 4; ++ct) {
        v8s wf = *(const v8s*)(wvb + (w * 64 + ct * 16 + li) * 256 + ks * 32 + g * 8);
#pragma unroll
        for (int nt = 0; nt < 4; ++nt) acc[ct][nt] = MFMA16(wf, xf[nt], acc[ct][nt]);
      }
    }
#pragma unroll
    for (int ct = 0; ct < 4; ++ct)
#pragma unroll
      for (int r = 0; r < 4; ++r) {
        int c = w * 64 + ct * 16 + 4 * g + r;
        float bias = bv[c];
#pragma unroll
        for (int nt = 0; nt < 4; ++nt) {
          int n = n0 + nt * 16 + li;
          vb[((size_t)(b * CCH + c)) * NPIX + n] = f2bf(acc[ct][nt][r] + bias);
        }
      }
  }
}

// ---------------- fused flash attention + residual (symmetric waves) ----------------
// 4 waves / 256 threads. Wave w owns rows [i0+16w, i0+16w+16) COMPLETELY:
// QK^T (swapped -> row i=li lane-local), softmax with lane-local m/ls,
// P->B-frag transpose via per-wave PRIVATE LDS (no barrier), PV over all 256
// channels from block-staged V. Only sync: one symmetric barrier per 32-j
// chunk for the double-buffered V stage (global_load_lds, counted vmcnt(2),
// never drained). V LDS layout XOR-swizzled both sides (conflict-free).
__global__ __launch_bounds__(256, 2) void attn_kernel(
    const unsigned short* __restrict__ qb, const unsigned short* __restrict__ kb,
    const unsigned short* __restrict__ vb, const float* __restrict__ x,
    const float* __restrict__ gamma, float* __restrict__ out) {
  __shared__ __align__(16) char vlds[2][16384];   // [buf][256c x 32j bf16], swizzled
  __shared__ __align__(16) char plds[4][1024];    // per-wave [16i x 32j bf16], swizzled
  int bx = blockIdx.x;
  int wg = (bx & 7) * 64 + (bx >> 3);   // XCD swizzle: XCD b holds batch b's K/V in L2
  int b = wg >> 6, it = wg & 63;
  int i0 = it * 64;
  int w = threadIdx.x >> 6, lane = threadIdx.x & 63, g = lane >> 4, li = lane & 15;

  // ---- staging source (inverse-swizzled global addr; LDS dest linear) ----
  int c0 = w * 16 + (lane >> 2);
  int srccol = ((lane & 3) ^ ((lane >> 3) & 3)) << 4;
  const char* vsrc = (const char*)vb + (((size_t)(b * CCH + c0) * NPIX) << 1) + srccol;
  // ---- swizzled in-LDS read bases (per-lane byte offsets) ----
  int vread0 = li * 64 + ((g ^ ((li >> 1) & 3)) << 4);        // V: row ct*16+li at +ct*1024
  int psw = (li & 3) << 4;
  char* pw = &plds[w][0] + li * 64;                            // P private row base
  int po0 = (8 * g) ^ psw;                                     // write jt=0 (b64)
  int po1 = (32 + 8 * g) ^ psw;                                // write jt=1 (b64)
  int prd = (16 * g) ^ psw;                                    // read (b128)

  float mraw = -1e30f, ml2 = -1.44e30f, ls = 0.f;
  v4f acc[16];
#pragma unroll
  for (int ct = 0; ct < 16; ++ct) acc[ct] = (v4f){0.f, 0.f, 0.f, 0.f};
  const v4f vzero = {0.f, 0.f, 0.f, 0.f};

  // ---- prologue: qf, stage chunk 0, K chunk 0 ----
  v8s qf = *(const v8s*)(qb + ((size_t)(b * NPIX + i0 + w * 16 + li)) * 32 + g * 8);
  {
    char* dp = &vlds[0][0] + w * 1024;
    gld16(vsrc, dp);
    gld16(vsrc + 524288, dp + 4096);
    gld16(vsrc + 1048576, dp + 8192);
    gld16(vsrc + 1572864, dp + 12288);
  }
  asm volatile("" ::: "memory");   // pin order: stage loads before kf loads (vmcnt count)
  const unsigned short* kbase = kb + ((size_t)(b * NPIX) + li) * 32 + g * 8;
  v8s kf0 = *(const v8s*)(kbase);
  v8s kf1 = *(const v8s*)(kbase + 512);

  for (int jc = 0; jc < 128; ++jc) {
    int bs = jc & 1;
    // own stage(jc) complete (2 newer kf loads may remain in flight)
    asm volatile("s_waitcnt vmcnt(2)" ::: "memory");
    __builtin_amdgcn_s_barrier();    // all waves staged buf[bs]; all done reading buf[bs^1]
    asm volatile("" ::: "memory");
    // ---- S^T = K Q^T: lane holds S[i=li][j = jc*32 + jt*16 + 4g + r] ----
    v4f s0 = MFMA16(kf0, qf, vzero);
    v4f s1 = MFMA16(kf1, qf, vzero);
    // ---- lane-local online softmax (defer-max THR=8) ----
    float pmax = fmaxf(fmaxf(fmaxf(s0[0], s0[1]), fmaxf(s0[2], s0[3])),
                       fmaxf(fmaxf(s1[0], s1[1]), fmaxf(s1[2], s1[3])));
    pmax = fmaxf(pmax, __shfl_xor(pmax, 16, 64));
    pmax = fmaxf(pmax, __shfl_xor(pmax, 32, 64));
    bool upd = pmax > mraw + 8.f;
    float nml2 = upd ? pmax * LOG2E : ml2;
    float fsc = __builtin_amdgcn_exp2f(ml2 - nml2);
    if (upd) { mraw = pmax; ml2 = nml2; }
    float p00 = __builtin_amdgcn_exp2f(fmaf(s0[0], LOG2E, -nml2));
    float p01 = __builtin_amdgcn_exp2f(fmaf(s0[1], LOG2E, -nml2));
    float p02 = __builtin_amdgcn_exp2f(fmaf(s0[2], LOG2E, -nml2));
    float p03 = __builtin_amdgcn_exp2f(fmaf(s0[3], LOG2E, -nml2));
    float p10 = __builtin_amdgcn_exp2f(fmaf(s1[0], LOG2E, -nml2));
    float p11 = __builtin_amdgcn_exp2f(fmaf(s1[1], LOG2E, -nml2));
    float p12 = __builtin_amdgcn_exp2f(fmaf(s1[2], LOG2E, -nml2));
    float p13 = __builtin_amdgcn_exp2f(fmaf(s1[3], LOG2E, -nml2));
    float rs = ((p00 + p01) + (p02 + p03)) + ((p10 + p11) + (p12 + p13));
    rs += __shfl_xor(rs, 16, 64);
    rs += __shfl_xor(rs, 32, 64);
    ls = ls * fsc + rs;
    // ---- publish P to PRIVATE lds (same-wave, no barrier) ----
    v2u pa, pb2;
    pa.x = cvtpk(p00, p01);  pa.y = cvtpk(p02, p03);
    pb2.x = cvtpk(p10, p11); pb2.y = cvtpk(p12, p13);
    *(v2u*)(pw + po0) = pa;
    *(v2u*)(pw + po1) = pb2;
    // ---- rescale acc (skip when no row's max grew) ----
    if (__any(upd)) {
#pragma unroll
      for (int ct = 0; ct < 16; ++ct) acc[ct] = acc[ct] * fsc;
    }
    // ---- P B-frag read (compiler inserts lgkm wait) ----
    v8s pf = *(const v8s*)(pw + prd);
    // ---- PV: O^T[c][i] += V[c][j] P^T[j][i] over all 256 channels ----
    const char* vbase = &vlds[bs][0] + vread0;
#pragma unroll
    for (int ct = 0; ct < 16; ++ct) {
      v8s vf = *(const v8s*)(vbase + ct * 1024);
      acc[ct] = MFMA16(vf, pf, acc[ct]);
    }
    // ---- stage chunk jc+1 into buf[bs^1] (in flight across next barrier) ----
    int jn = (jc < 127) ? jc + 1 : 127;
    {
      const char* sp = vsrc + (size_t)jn * 64;
      char* dp = &vlds[bs ^ 1][0] + w * 1024;
      gld16(sp, dp);
      gld16(sp + 524288, dp + 4096);
      gld16(sp + 1048576, dp + 8192);
      gld16(sp + 1572864, dp + 12288);
    }
    asm volatile("" ::: "memory");   // pin order: stage before kf (vmcnt counting)
    // ---- K prefetch chunk jn ----
    const unsigned short* kp = kbase + (size_t)(jn * 32) * 32;
    kf0 = *(const v8s*)(kp);
    kf1 = *(const v8s*)(kp + 512);
  }
  // ---- epilogue: out = gamma * O / l + x (all state lane-local) ----
  float inv = gamma[0] / ls;
#pragma unroll
  for (int ct = 0; ct < 16; ++ct)
#pragma unroll
    for (int r = 0; r < 4; ++r) {
      int c = ct * 16 + 4 * g + r;
      size_t idx = ((size_t)(b * CCH + c)) * NPIX + i0 + w * 16 + li;
      out[idx] = acc[ct][r] * inv + x[idx];
    }
}

extern "C" void kernel_launch(void* const* d_in, const int* in_sizes, int n_in,
                              void* d_out, int out_size, void* d_ws, size_t ws_size,
                              hipStream_t stream) {
  const float* x = (const float*)d_in[0];
  const float* Wq = (const float*)d_in[1];
  const float* bq = (const float*)d_in[2];
  const float* Wk = (const float*)d_in[3];
  const float* bk = (const float*)d_in[4];
  const float* Wv = (const float*)d_in[5];
  const float* bv = (const float*)d_in[6];
  const float* gamma = (const float*)d_in[7];
  float* out = (float*)d_out;
  char* ws = (char*)d_ws;
  unsigned short* xT  = (unsigned short*)(ws);                    // 16 MB
  unsigned short* qb  = (unsigned short*)(ws + 16777216);         // 2 MB
  unsigned short* kb  = (unsigned short*)(ws + 18874368);         // 2 MB
  unsigned short* vb  = (unsigned short*)(ws + 20971520);         // 16 MB
  unsigned short* wqk = (unsigned short*)(ws + 37748736);         // 32 KB
  unsigned short* wvb = (unsigned short*)(ws + 37781504);         // 128 KB

  prep1_kernel<<<2112, 256, 0, stream>>>(x, Wq, Wk, Wv, xT, wqk, wvb);
  prep2_kernel<<<1024, 256, 0, stream>>>(xT, wqk, wvb, bq, bk, bv, qb, kb, vb);
  attn_kernel<<<512, 256, 0, stream>>>(qb, kb, vb, x, gamma, out);
}

// Round 8
// 284.691 us; speedup vs baseline: 1.0346x; 1.0346x over previous
//
#include <hip/hip_runtime.h>

#define LOG2E 1.44269504088896340736f

typedef short v8s __attribute__((ext_vector_type(8)));
typedef float v4f __attribute__((ext_vector_type(4)));
typedef unsigned int v2u __attribute__((ext_vector_type(2)));

__device__ __forceinline__ unsigned short f2bf(float f) {
  unsigned int u = __float_as_uint(f);
  u += 0x7fffu + ((u >> 16) & 1u);   // RNE
  return (unsigned short)(u >> 16);
}

__device__ __forceinline__ float bf2f(unsigned short u) {
  return __uint_as_float((unsigned int)u << 16);
}

__device__ __forceinline__ unsigned int cvtpk(float lo, float hi) {
  unsigned int r;
  asm("v_cvt_pk_bf16_f32 %0, %1, %2" : "=v"(r) : "v"(lo), "v"(hi));
  return r;
}

#define MFMA16(a, b, c) __builtin_amdgcn_mfma_f32_16x16x32_bf16((a), (b), (c), 0, 0, 0)

static const int CCH = 256, NPIX = 4096;

// ---------------- weights -> bf16 ----------------
__global__ void wconv_kernel(const float* __restrict__ Wq, const float* __restrict__ Wk,
                             const float* __restrict__ Wv, unsigned short* __restrict__ wqk,
                             unsigned short* __restrict__ wvb) {
  int idx = blockIdx.x * 256 + threadIdx.x;
  int tot = 64 * 256 + 256 * 256;
  for (int i = idx; i < tot; i += gridDim.x * 256) {
    if (i < 64 * 256) {
      float v = (i < 32 * 256) ? Wq[i] : Wk[i - 32 * 256];
      wqk[i] = f2bf(v);
    } else {
      wvb[i - 64 * 256] = f2bf(Wv[i - 64 * 256]);
    }
  }
}

// ---------------- fused prep: x-transpose (LDS only) + q/k/v projections ----------------
// One pass over x: block = (b, 64-pixel n-tile). 4 slabs of 64 channels are
// staged f32 -> transposed to bf16 xl[64 n][256 c] (pad 8). Then MFMA phase
// computes q,k (wave w: rows 16w..16w+15) and v (wave w: channels 64w..64w+63)
// reading A/B fragments straight from xl. xT never touches HBM.
__global__ __launch_bounds__(256, 2) void prep_kernel(
    const float* __restrict__ x, const unsigned short* __restrict__ wqk,
    const unsigned short* __restrict__ wvb, const float* __restrict__ bq,
    const float* __restrict__ bk, const float* __restrict__ bv,
    unsigned short* __restrict__ qb, unsigned short* __restrict__ kb,
    unsigned short* __restrict__ vb) {
  __shared__ float tile[64][65];
  __shared__ unsigned short xl[64][264];
  int bid = blockIdx.x;                 // 8 * 64
  int b = bid >> 6;
  int n0 = (bid & 63) * 64;
  int t = threadIdx.x;
#pragma unroll
  for (int s = 0; s < 4; ++s) {
    int c0 = s * 64;
    const float* xp = x + ((size_t)b * CCH + c0) * NPIX + n0;
#pragma unroll
    for (int p = 0; p < 4; ++p) {
      int cc = p * 16 + (t >> 4);
      int nn = (t & 15) * 4;
      float4 v = *(const float4*)(xp + (size_t)cc * NPIX + nn);
      tile[cc][nn] = v.x; tile[cc][nn + 1] = v.y;
      tile[cc][nn + 2] = v.z; tile[cc][nn + 3] = v.w;
    }
    __syncthreads();
#pragma unroll
    for (int p = 0; p < 8; ++p) {
      int nn = p * 8 + (t >> 5);
      int cc = (t & 31) * 2;
      unsigned int pk = (unsigned int)f2bf(tile[cc][nn]) |
                        ((unsigned int)f2bf(tile[cc + 1][nn]) << 16);
      *(unsigned int*)(&xl[nn][c0 + cc]) = pk;
    }
    __syncthreads();
  }
  int w = t >> 6, lane = t & 63, g = lane >> 4, li = lane & 15;
  // ---- q/k: wave w rows n0+16w .. +16 ----
  {
    v4f acc[4];
#pragma unroll
    for (int dt = 0; dt < 4; ++dt) acc[dt] = (v4f){0.f, 0.f, 0.f, 0.f};
#pragma unroll
    for (int ks = 0; ks < 8; ++ks) {
      v8s a = *(const v8s*)(&xl[16 * w + li][ks * 32 + g * 8]);
#pragma unroll
      for (int dt = 0; dt < 4; ++dt) {
        v8s bf = *(const v8s*)(wqk + (dt * 16 + li) * 256 + ks * 32 + g * 8);
        acc[dt] = MFMA16(a, bf, acc[dt]);
      }
    }
#pragma unroll
    for (int dt = 0; dt < 4; ++dt) {
      int d = (dt & 1) * 16 + li;
      float bias = (dt < 2) ? bq[d] : bk[d];
      unsigned short* op = (dt < 2) ? qb : kb;
#pragma unroll
      for (int r = 0; r < 4; ++r) {
        int n = n0 + 16 * w + 4 * g + r;
        op[((size_t)(b * NPIX + n)) * 32 + d] = f2bf(acc[dt][r] + bias);
      }
    }
  }
  // ---- v: wave w channels 64w .. +64 ----
  {
    v4f acc[4][4];
#pragma unroll
    for (int ct = 0; ct < 4; ++ct)
#pragma unroll
      for (int nt = 0; nt < 4; ++nt) acc[ct][nt] = (v4f){0.f, 0.f, 0.f, 0.f};
#pragma unroll
    for (int ks = 0; ks < 8; ++ks) {
      v8s xf[4];
#pragma unroll
      for (int nt = 0; nt < 4; ++nt)
        xf[nt] = *(const v8s*)(&xl[nt * 16 + li][ks * 32 + g * 8]);
#pragma unroll
      for (int ct = 0; ct < 4; ++ct) {
        v8s wf = *(const v8s*)(wvb + (w * 64 + ct * 16 + li) * 256 + ks * 32 + g * 8);
#pragma unroll
        for (int nt = 0; nt < 4; ++nt) acc[ct][nt] = MFMA16(wf, xf[nt], acc[ct][nt]);
      }
    }
#pragma unroll
    for (int ct = 0; ct < 4; ++ct)
#pragma unroll
      for (int r = 0; r < 4; ++r) {
        int c = w * 64 + ct * 16 + 4 * g + r;
        float bias = bv[c];
#pragma unroll
        for (int nt = 0; nt < 4; ++nt) {
          int n = n0 + nt * 16 + li;
          vb[((size_t)(b * CCH + c)) * NPIX + n] = f2bf(acc[ct][nt][r] + bias);
        }
      }
  }
}

// ---------------- fused flash attention (split-j) ----------------
// r5-verified 8-wave kernel, j-range split across JQ block-slabs.
// JQ==1: full epilogue (gamma*O/l + x). JQ>1: write unnormalized O bf16
// partials + per-row (m2, l) f32; combine kernel finishes.
#define PSWZ(il, jl) (((il) * 64 + (jl)) ^ (((il) & 7) << 3))
template <int JQ>
__global__ __launch_bounds__(512, 4) void attn_kernel(
    const unsigned short* __restrict__ qb, const unsigned short* __restrict__ kb,
    const unsigned short* __restrict__ vb, const float* __restrict__ x,
    const float* __restrict__ gamma, float* __restrict__ out,
    unsigned short* __restrict__ Opart, float* __restrict__ ml) {
  __shared__ __align__(16) unsigned short pbuf[2][64 * 64];
  __shared__ float fbuf[2][64];
  __shared__ float lbuf[64];
  int bx = blockIdx.x;
  int jq = bx >> 9;
  int bxl = bx & 511;
  int wg = (bxl & 7) * 64 + (bxl >> 3);   // XCD swizzle: batch-affine L2 for K/V
  int b = wg >> 6, it = wg & 63;
  int i0 = it * 64;
  int w = threadIdx.x >> 6, lane = threadIdx.x & 63, g = lane >> 4, li = lane & 15;
  bool prod = (w < 4);
  const int NC = 64 / JQ;
  int c0s = jq * NC, c0e = c0s + NC;

  float mraw = -1e30f, ml2 = -1.44e30f, ls = 0.f;
  v4f acc[2][4];
#pragma unroll
  for (int ct = 0; ct < 2; ++ct)
#pragma unroll
    for (int itl = 0; itl < 4; ++itl) acc[ct][itl] = (v4f){0.f, 0.f, 0.f, 0.f};
  const v4f vzero = {0.f, 0.f, 0.f, 0.f};

  const unsigned short* vb0 = vb + ((size_t)(b * CCH + w * 32 + li)) * NPIX + g * 8;
  const unsigned short* vbc[2];
#pragma unroll
  for (int ct = 0; ct < 2; ++ct) vbc[ct] = vb0 + (size_t)ct * 16 * NPIX;

  const unsigned short* kbase = kb + ((size_t)b * NPIX + li) * 32 + g * 8;
  v8s qf = {0, 0, 0, 0, 0, 0, 0, 0};
  v8s kf[4];
  if (prod) {
    qf = *(const v8s*)(qb + ((size_t)(b * NPIX + i0 + w * 16 + li)) * 32 + g * 8);
#pragma unroll
    for (int jt = 0; jt < 4; ++jt)
      kf[jt] = *(const v8s*)(kbase + (size_t)(c0s * 64 + jt * 16) * 32);
  }

  for (int jc = c0s; jc < c0e; ++jc) {
    int j0 = jc * 64, bsel = jc & 1;
    v8s vf[2][2];
#pragma unroll
    for (int ct = 0; ct < 2; ++ct)
#pragma unroll
      for (int sl = 0; sl < 2; ++sl)
        vf[ct][sl] = *(const v8s*)(vbc[ct] + j0 + sl * 32);
    if (prod) {
      __builtin_amdgcn_s_setprio(1);
      v4f s[4];
#pragma unroll
      for (int jt = 0; jt < 4; ++jt) s[jt] = MFMA16(kf[jt], qf, vzero);
      int jn = (jc < c0e - 1) ? j0 + 64 : j0;
#pragma unroll
      for (int jt = 0; jt < 4; ++jt)
        kf[jt] = *(const v8s*)(kbase + (size_t)(jn + jt * 16) * 32);
      float t0 = fmaxf(fmaxf(s[0][0], s[0][1]), fmaxf(s[0][2], s[0][3]));
      float t1 = fmaxf(fmaxf(s[1][0], s[1][1]), fmaxf(s[1][2], s[1][3]));
      float t2 = fmaxf(fmaxf(s[2][0], s[2][1]), fmaxf(s[2][2], s[2][3]));
      float t3 = fmaxf(fmaxf(s[3][0], s[3][1]), fmaxf(s[3][2], s[3][3]));
      float pmax = fmaxf(fmaxf(t0, t1), fmaxf(t2, t3));
      pmax = fmaxf(pmax, __shfl_xor(pmax, 16, 64));
      pmax = fmaxf(pmax, __shfl_xor(pmax, 32, 64));
      bool upd = pmax > mraw + 8.f;
      float nml2 = upd ? pmax * LOG2E : ml2;
      float fsc = __builtin_amdgcn_exp2f(ml2 - nml2);
      if (upd) { mraw = pmax; ml2 = nml2; }
      int il = w * 16 + li;
      float rs = 0.f;
#pragma unroll
      for (int jt = 0; jt < 4; ++jt) {
        float p0 = __builtin_amdgcn_exp2f(fmaf(s[jt][0], LOG2E, -nml2));
        float p1 = __builtin_amdgcn_exp2f(fmaf(s[jt][1], LOG2E, -nml2));
        float p2 = __builtin_amdgcn_exp2f(fmaf(s[jt][2], LOG2E, -nml2));
        float p3 = __builtin_amdgcn_exp2f(fmaf(s[jt][3], LOG2E, -nml2));
        rs += (p0 + p1) + (p2 + p3);
        v2u pk;
        pk.x = cvtpk(p0, p1);
        pk.y = cvtpk(p2, p3);
        *(v2u*)(&pbuf[bsel][PSWZ(il, jt * 16 + 4 * g)]) = pk;
      }
      rs += __shfl_xor(rs, 16, 64);
      rs += __shfl_xor(rs, 32, 64);
      ls = ls * fsc + rs;
      if (g == 0) fbuf[bsel][il] = fsc;
      asm volatile("s_waitcnt lgkmcnt(0)" ::: "memory");
      __builtin_amdgcn_s_setprio(0);
    }
    __builtin_amdgcn_s_barrier();
    asm volatile("" ::: "memory");
    float fv[4];
#pragma unroll
    for (int itl = 0; itl < 4; ++itl) fv[itl] = fbuf[bsel][itl * 16 + li];
    int anyr = (fv[0] != 1.f) | (fv[1] != 1.f) | (fv[2] != 1.f) | (fv[3] != 1.f);
    if (__any(anyr)) {
#pragma unroll
      for (int itl = 0; itl < 4; ++itl)
#pragma unroll
        for (int ct = 0; ct < 2; ++ct) acc[ct][itl] = acc[ct][itl] * fv[itl];
    }
#pragma unroll
    for (int itl = 0; itl < 4; ++itl) {
      v8s pf[2];
#pragma unroll
      for (int sl = 0; sl < 2; ++sl)
        pf[sl] = *(const v8s*)(&pbuf[bsel][PSWZ(itl * 16 + li, sl * 32 + g * 8)]);
#pragma unroll
      for (int ct = 0; ct < 2; ++ct)
#pragma unroll
        for (int sl = 0; sl < 2; ++sl) acc[ct][itl] = MFMA16(vf[ct][sl], pf[sl], acc[ct][itl]);
    }
  }
  if constexpr (JQ == 1) {
    // ---- final epilogue: out = gamma * O / l + x ----
    if (prod && g == 0) lbuf[w * 16 + li] = ls;
    __syncthreads();
    float gm = gamma[0];
#pragma unroll
    for (int itl = 0; itl < 4; ++itl) {
      float inv = gm / lbuf[itl * 16 + li];
#pragma unroll
      for (int ct = 0; ct < 2; ++ct)
#pragma unroll
        for (int r = 0; r < 4; ++r) {
          int c = w * 32 + ct * 16 + 4 * g + r;
          size_t idx = ((size_t)(b * CCH + c)) * NPIX + i0 + itl * 16 + li;
          out[idx] = acc[ct][itl][r] * inv + x[idx];
        }
    }
  } else {
    // ---- partial epilogue: unnormalized O (bf16) + per-row m2/l (f32) ----
    if (prod && g == 0) {
      int il = w * 16 + li;
      ml[((size_t)(jq * 512 + wg)) * 128 + il] = ml2;
      ml[((size_t)(jq * 512 + wg)) * 128 + 64 + il] = ls;
    }
    unsigned short* ob = Opart + ((size_t)(jq * 512 + wg)) * 256 * 64;
#pragma unroll
    for (int itl = 0; itl < 4; ++itl)
#pragma unroll
      for (int ct = 0; ct < 2; ++ct)
#pragma unroll
        for (int r = 0; r < 4; ++r) {
          int c = w * 32 + ct * 16 + 4 * g + r;
          ob[(size_t)c * 64 + itl * 16 + li] = f2bf(acc[ct][itl][r]);
        }
  }
}

// ---------------- combine: rescale-sum partials, normalize, add residual ----------------
template <int JQ>
__global__ __launch_bounds__(256) void combine_kernel(
    const unsigned short* __restrict__ Opart, const float* __restrict__ ml,
    const float* __restrict__ x, const float* __restrict__ gamma,
    float* __restrict__ out) {
  int wg = blockIdx.x;                  // b*64 + it (plain order)
  int t = threadIdx.x;
  int il = t & 63, cq = t >> 6;
  float m_g = -1e30f;
#pragma unroll
  for (int q = 0; q < JQ; ++q)
    m_g = fmaxf(m_g, ml[((size_t)(q * 512 + wg)) * 128 + il]);
  float w_q[JQ], l_g = 0.f;
#pragma unroll
  for (int q = 0; q < JQ; ++q) {
    float wq = __builtin_amdgcn_exp2f(ml[((size_t)(q * 512 + wg)) * 128 + il] - m_g);
    w_q[q] = wq;
    l_g += wq * ml[((size_t)(q * 512 + wg)) * 128 + 64 + il];
  }
  int b = wg >> 6;
  int i0 = (wg & 63) * 64;
  float gm = gamma[0] / l_g;
  const unsigned short* ob = Opart + (size_t)wg * 256 * 64;
#pragma unroll 4
  for (int c = cq * 64; c < cq * 64 + 64; ++c) {
    float o = 0.f;
#pragma unroll
    for (int q = 0; q < JQ; ++q)
      o += w_q[q] * bf2f(ob[(size_t)q * 512 * 256 * 64 + (size_t)c * 64 + il]);
    size_t idx = ((size_t)(b * CCH + c)) * NPIX + i0 + il;
    out[idx] = o * gm + x[idx];
  }
}

extern "C" void kernel_launch(void* const* d_in, const int* in_sizes, int n_in,
                              void* d_out, int out_size, void* d_ws, size_t ws_size,
                              hipStream_t stream) {
  const float* x = (const float*)d_in[0];
  const float* Wq = (const float*)d_in[1];
  const float* bq = (const float*)d_in[2];
  const float* Wk = (const float*)d_in[3];
  const float* bk = (const float*)d_in[4];
  const float* Wv = (const float*)d_in[5];
  const float* bv = (const float*)d_in[6];
  const float* gamma = (const float*)d_in[7];
  float* out = (float*)d_out;
  char* ws = (char*)d_ws;
  // layout (bytes)
  unsigned short* qb    = (unsigned short*)(ws);                  // 2 MB
  unsigned short* kb    = (unsigned short*)(ws + 2097152);        // 2 MB
  unsigned short* vb    = (unsigned short*)(ws + 4194304);        // 16 MB
  unsigned short* wqk   = (unsigned short*)(ws + 20971520);       // 32 KB
  unsigned short* wvb   = (unsigned short*)(ws + 21004288);       // 128 KB
  float*          mlp   = (float*)(ws + 21135360);                // <=1 MB
  unsigned short* Opart = (unsigned short*)(ws + 22282240);       // JQ*16 MB

  int JQ = 1;
  if (ws_size >= (size_t)22282240 + (size_t)4 * 16777216) JQ = 4;
  else if (ws_size >= (size_t)22282240 + (size_t)2 * 16777216) JQ = 2;

  wconv_kernel<<<80, 256, 0, stream>>>(Wq, Wk, Wv, wqk, wvb);
  prep_kernel<<<512, 256, 0, stream>>>(x, wqk, wvb, bq, bk, bv, qb, kb, vb);
  if (JQ == 4) {
    attn_kernel<4><<<2048, 512, 0, stream>>>(qb, kb, vb, x, gamma, out, Opart, mlp);
    combine_kernel<4><<<512, 256, 0, stream>>>(Opart, mlp, x, gamma, out);
  } else if (JQ == 2) {
    attn_kernel<2><<<1024, 512, 0, stream>>>(qb, kb, vb, x, gamma, out, Opart, mlp);
    combine_kernel<2><<<512, 256, 0, stream>>>(Opart, mlp, x, gamma, out);
  } else {
    attn_kernel<1><<<512, 512, 0, stream>>>(qb, kb, vb, x, gamma, out, Opart, mlp);
  }
}